// Round 1
// baseline (719.879 us; speedup 1.0000x reference)
//
#include <hip/hip_runtime.h>
#include <hip/hip_bf16.h>

// ESA_SMILES fused pipeline for MI355X (gfx950).
// Key identity: feat = LN(x)@W1^T+b1 -> cap;  cap@W2^T+b2
//             = LN(x)@(W2*W1)^T + (W2*b1+b2)
// so both cap and feat are GEMMs from the same y = LN(x), fragment-aligned.
// out[b,d] = sum_n exp(feat[n,d])*cap[n,d] / sum_n exp(feat[n,d])  (n in batch b)

typedef short short8 __attribute__((ext_vector_type(8)));   // 8 x bf16
typedef float f32x4 __attribute__((ext_vector_type(4)));

__device__ inline short f2bf(float f) {
    unsigned u = __float_as_uint(f);
    u += 0x7fffu + ((u >> 16) & 1u);     // round-to-nearest-even
    return (short)(u >> 16);
}

// ---------------------------------------------------------------------------
// Prep 1: W12 = W2 @ W1 (fp32, tiled) -> bf16; W1 -> bf16; b12 = W2@b1 + b2
// grid 64 blocks x 256 threads; 8x8 tiles of 64x64
// ---------------------------------------------------------------------------
__global__ __launch_bounds__(256)
void esa_prep_w12(const float* __restrict__ W1, const float* __restrict__ W2,
                  const float* __restrict__ b1v, const float* __restrict__ b2v,
                  short* __restrict__ W1b, short* __restrict__ W12b,
                  float* __restrict__ b12) {
    __shared__ float As[64][65];   // W2 tile: [i][k]
    __shared__ float Bs[64][65];   // W1 tile: [k][j]
    const int ti = blockIdx.x >> 3;
    const int tj = blockIdx.x & 7;
    const int tx = threadIdx.x & 15;
    const int ty = threadIdx.x >> 4;
    float acc[4][4] = {};
    for (int k0 = 0; k0 < 512; k0 += 64) {
        for (int l = threadIdx.x; l < 64 * 64; l += 256) {
            int r = l >> 6, c = l & 63;
            As[r][c] = W2[(size_t)(ti * 64 + r) * 512 + k0 + c];
            Bs[r][c] = W1[(size_t)(k0 + r) * 512 + tj * 64 + c];
        }
        __syncthreads();
#pragma unroll 8
        for (int kk = 0; kk < 64; ++kk) {
            float av[4], bv[4];
#pragma unroll
            for (int a = 0; a < 4; ++a) av[a] = As[ty * 4 + a][kk];
#pragma unroll
            for (int b = 0; b < 4; ++b) bv[b] = Bs[kk][tx * 4 + b];
#pragma unroll
            for (int a = 0; a < 4; ++a)
#pragma unroll
                for (int b = 0; b < 4; ++b) acc[a][b] += av[a] * bv[b];
        }
        __syncthreads();
    }
#pragma unroll
    for (int a = 0; a < 4; ++a)
#pragma unroll
        for (int b = 0; b < 4; ++b)
            W12b[(size_t)(ti * 64 + ty * 4 + a) * 512 + tj * 64 + tx * 4 + b] =
                f2bf(acc[a][b]);
    // W1 -> bf16 (strided over whole matrix)
    int gid = blockIdx.x * 256 + threadIdx.x;
    for (int idx = gid; idx < 512 * 512; idx += 64 * 256) W1b[idx] = f2bf(W1[idx]);
    // b12 = W2 @ b1 + b2 (first 512 global threads)
    if (gid < 512) {
        float s = b2v[gid];
        for (int k = 0; k < 512; ++k) s += W2[(size_t)gid * 512 + k] * b1v[k];
        b12[gid] = s;
    }
}

// ---------------------------------------------------------------------------
// Prep 2: per-batch offsets via binary search on sorted data_batch, then
// batch-boundary-aligned 64-node chunk entries {batch, start, valid}.
// single block, 256 threads. Requires B <= 512.
// ---------------------------------------------------------------------------
__global__ __launch_bounds__(256)
void esa_prep_entries(const int* __restrict__ db, int T, int B,
                      int4* __restrict__ entries, int maxent) {
    __shared__ int off[513];
    __shared__ int nch[512];
    __shared__ int scan[513];
    for (int t = threadIdx.x; t <= B; t += 256) {
        if (t == B) {
            off[t] = T;
        } else {
            int lo = 0, hi = T;
            while (lo < hi) {
                int mid = (lo + hi) >> 1;
                if (db[mid] < t) lo = mid + 1; else hi = mid;
            }
            off[t] = lo;
        }
    }
    __syncthreads();
    for (int t = threadIdx.x; t < B; t += 256)
        nch[t] = (off[t + 1] - off[t] + 63) >> 6;
    __syncthreads();
    if (threadIdx.x == 0) {
        int s = 0;
        for (int i = 0; i < B; ++i) { scan[i] = s; s += nch[i]; }
        scan[B] = s;
    }
    __syncthreads();
    for (int t = threadIdx.x; t < B; t += 256) {
        int cnt = off[t + 1] - off[t];
        for (int j = 0; j < nch[t]; ++j) {
            int v = cnt - j * 64;
            if (v > 64) v = 64;
            entries[scan[t] + j] = make_int4(t, off[t] + j * 64, v, 0);
        }
    }
    int total = scan[B];
    for (int i = total + threadIdx.x; i < maxent; i += 256)
        entries[i] = make_int4(0, 0, 0, 0);
}

// ---------------------------------------------------------------------------
// Main fused kernel: one block = 64 nodes of one batch.
// Phase 1: LayerNorm -> y bf16 in LDS (stride 520: 2-way bank alias = free)
// Phase 2: dual GEMM (cap via W1b, feat via W12b) with 16x16x32 bf16 MFMA,
//          per-wave 128-col stripe, groups of 2 n-tiles, shared A-frags.
// Epilogue: e=exp(feat), reduce sum(e), sum(e*cap) over 64 rows, atomicAdd.
// ---------------------------------------------------------------------------
#define LSTRIDE 520

__global__ __launch_bounds__(256, 2)
void esa_fused(const float* __restrict__ x, const float* __restrict__ gamma,
               const float* __restrict__ beta, const short* __restrict__ W1b,
               const short* __restrict__ W12b, const float* __restrict__ b1,
               const float* __restrict__ b12, const int4* __restrict__ entries,
               float* __restrict__ num, float* __restrict__ den) {
    __shared__ short ylds[64 * LSTRIDE];   // 66,560 B -> 2 blocks/CU
    const int4 e = entries[blockIdx.x];
    const int bat = e.x, start = e.y, valid = e.z;
    if (valid <= 0) return;

    const int tid = threadIdx.x;
    const int wave = tid >> 6;
    const int lane = tid & 63;
    const int quad = lane >> 4;
    const int l16 = lane & 15;

    // ---- Phase 1: LayerNorm. wave handles rows wave*16 .. +15, lane owns 8 cols
    const float4 g0 = *(const float4*)(gamma + lane * 8);
    const float4 g1 = *(const float4*)(gamma + lane * 8 + 4);
    const float4 be0 = *(const float4*)(beta + lane * 8);
    const float4 be1 = *(const float4*)(beta + lane * 8 + 4);

    for (int r = 0; r < 16; ++r) {
        const int m = wave * 16 + r;
        short8 outv = {0, 0, 0, 0, 0, 0, 0, 0};
        if (m < valid) {   // wave-uniform branch
            const float* xr = x + (size_t)(start + m) * 512 + lane * 8;
            const float4 a = *(const float4*)xr;
            const float4 b = *(const float4*)(xr + 4);
            float s = a.x + a.y + a.z + a.w + b.x + b.y + b.z + b.w;
            float ss = a.x * a.x + a.y * a.y + a.z * a.z + a.w * a.w +
                       b.x * b.x + b.y * b.y + b.z * b.z + b.w * b.w;
#pragma unroll
            for (int o = 1; o <= 32; o <<= 1) {
                s += __shfl_xor(s, o);
                ss += __shfl_xor(ss, o);
            }
            const float mu = s * (1.0f / 512.0f);
            const float var = ss * (1.0f / 512.0f) - mu * mu;
            const float rstd = rsqrtf(var + 1e-5f);
            outv[0] = f2bf((a.x - mu) * rstd * g0.x + be0.x);
            outv[1] = f2bf((a.y - mu) * rstd * g0.y + be0.y);
            outv[2] = f2bf((a.z - mu) * rstd * g0.z + be0.z);
            outv[3] = f2bf((a.w - mu) * rstd * g0.w + be0.w);
            outv[4] = f2bf((b.x - mu) * rstd * g1.x + be1.x);
            outv[5] = f2bf((b.y - mu) * rstd * g1.y + be1.y);
            outv[6] = f2bf((b.z - mu) * rstd * g1.z + be1.z);
            outv[7] = f2bf((b.w - mu) * rstd * g1.w + be1.w);
        }
        *(short8*)&ylds[m * LSTRIDE + lane * 8] = outv;
    }
    __syncthreads();

    // ---- Phase 2: dual GEMM + epilogue. Wave owns cols [wave*128, +128).
    const int kbase = quad * 8;
    const short* ap = &ylds[l16 * LSTRIDE + kbase];

    for (int grp = 0; grp < 4; ++grp) {
        const int n0 = wave * 128 + grp * 32;
        f32x4 acc_c[2][4], acc_f[2][4];
#pragma unroll
        for (int nt = 0; nt < 2; ++nt)
#pragma unroll
            for (int mt = 0; mt < 4; ++mt) {
                acc_c[nt][mt] = (f32x4)0.0f;
                acc_f[nt][mt] = (f32x4)0.0f;
            }
        const short* w1p0 = W1b + (size_t)(n0 + l16) * 512 + kbase;
        const short* w1p1 = W1b + (size_t)(n0 + 16 + l16) * 512 + kbase;
        const short* w2p0 = W12b + (size_t)(n0 + l16) * 512 + kbase;
        const short* w2p1 = W12b + (size_t)(n0 + 16 + l16) * 512 + kbase;

#pragma unroll 2
        for (int k0 = 0; k0 < 16; ++k0) {
            short8 afr[4];
#pragma unroll
            for (int mt = 0; mt < 4; ++mt)
                afr[mt] = *(const short8*)(ap + mt * 16 * LSTRIDE + k0 * 32);
            const short8 bw10 = *(const short8*)(w1p0 + k0 * 32);
            const short8 bw11 = *(const short8*)(w1p1 + k0 * 32);
            const short8 bw20 = *(const short8*)(w2p0 + k0 * 32);
            const short8 bw21 = *(const short8*)(w2p1 + k0 * 32);
#pragma unroll
            for (int mt = 0; mt < 4; ++mt) {
                acc_c[0][mt] = __builtin_amdgcn_mfma_f32_16x16x32_bf16(
                    afr[mt], bw10, acc_c[0][mt], 0, 0, 0);
                acc_c[1][mt] = __builtin_amdgcn_mfma_f32_16x16x32_bf16(
                    afr[mt], bw11, acc_c[1][mt], 0, 0, 0);
                acc_f[0][mt] = __builtin_amdgcn_mfma_f32_16x16x32_bf16(
                    afr[mt], bw20, acc_f[0][mt], 0, 0, 0);
                acc_f[1][mt] = __builtin_amdgcn_mfma_f32_16x16x32_bf16(
                    afr[mt], bw21, acc_f[1][mt], 0, 0, 0);
            }
        }
        // Epilogue: C/D layout col=lane&15, row=quad*4+reg (m89-verified)
#pragma unroll
        for (int nt = 0; nt < 2; ++nt) {
            const int n = n0 + nt * 16 + l16;
            const float bb1 = b1[n];
            const float bb2 = b12[n];
            float se = 0.0f, sec = 0.0f;
#pragma unroll
            for (int mt = 0; mt < 4; ++mt) {
#pragma unroll
                for (int r2 = 0; r2 < 4; ++r2) {
                    const int m = mt * 16 + quad * 4 + r2;
                    const float cap = acc_c[nt][mt][r2] + bb1;
                    const float ft = acc_f[nt][mt][r2] + bb2;
                    if (m < valid) {
                        const float ev = __expf(ft);
                        se += ev;
                        sec += ev * cap;
                    }
                }
            }
            se += __shfl_xor(se, 16);
            se += __shfl_xor(se, 32);
            sec += __shfl_xor(sec, 16);
            sec += __shfl_xor(sec, 32);
            if (quad == 0) atomicAdd(&den[(size_t)bat * 512 + n], se);
            else if (quad == 1) atomicAdd(&num[(size_t)bat * 512 + n], sec);
        }
    }
}

__global__ __launch_bounds__(256)
void esa_finalize(const float* __restrict__ num, const float* __restrict__ den,
                  float* __restrict__ out, int n) {
    const int i = blockIdx.x * 256 + threadIdx.x;
    if (i < n) {
        const float d = den[i];
        out[i] = d > 0.0f ? num[i] / d : 0.0f;
    }
}

extern "C" void kernel_launch(void* const* d_in, const int* in_sizes, int n_in,
                              void* d_out, int out_size, void* d_ws, size_t ws_size,
                              hipStream_t stream) {
    const float* x = (const float*)d_in[0];
    const int* db = (const int*)d_in[1];
    // d_in[2] = max_nodes (unused: chunking is derived from actual counts)
    const float* gamma = (const float*)d_in[3];
    const float* beta = (const float*)d_in[4];
    const float* W1 = (const float*)d_in[5];
    const float* b1 = (const float*)d_in[6];
    const float* W2 = (const float*)d_in[7];
    const float* b2 = (const float*)d_in[8];
    float* out = (float*)d_out;

    const int C = in_sizes[3];        // 512
    const int D = in_sizes[6];        // 512
    const int T = in_sizes[0] / C;    // 131072
    const int B = out_size / D;       // 128
    const int maxent = B + (T + 63) / 64;   // upper bound on chunk entries

    char* ws = (char*)d_ws;
    short* W1b = (short*)(ws);                      // 512 KB
    short* W12b = (short*)(ws + 524288);            // 512 KB
    float* b12 = (float*)(ws + 1048576);            // 2 KB
    int4* entries = (int4*)(ws + 1050624);          // maxent*16
    size_t numoff = (1050624 + (size_t)maxent * 16 + 255) & ~(size_t)255;
    float* num = (float*)(ws + numoff);             // B*D*4
    float* den = (float*)(ws + numoff + (size_t)B * D * 4);

    hipMemsetAsync(num, 0, (size_t)B * D * 8, stream);
    esa_prep_w12<<<64, 256, 0, stream>>>(W1, W2, b1, b2, W1b, W12b, b12);
    esa_prep_entries<<<1, 256, 0, stream>>>(db, T, B, entries, maxent);
    esa_fused<<<maxent, 256, 0, stream>>>(x, gamma, beta, W1b, W12b, b1, b12,
                                          entries, num, den);
    esa_finalize<<<(B * D + 255) / 256, 256, 0, stream>>>(num, den, out, B * D);
}

// Round 3
// 656.544 us; speedup vs baseline: 1.0965x; 1.0965x over previous
//
#include <hip/hip_runtime.h>
#include <hip/hip_bf16.h>

// ESA_SMILES fused pipeline for MI355X (gfx950).
// Identity: cap = LN(x)@W1^T+b1 ; feat = cap@W2^T+b2 = LN(x)@(W2W1)^T+(W2b1+b2)
// -> both cap and feat are GEMMs from the same y = LN(x); softmax-weighted
// reduction happens in-register (fragments element-aligned).
// out[b,d] = sum_n exp(feat[n,d])*cap[n,d] / sum_n exp(feat[n,d])

typedef short short8 __attribute__((ext_vector_type(8)));   // 8 x bf16
typedef short short4v __attribute__((ext_vector_type(4)));
typedef float f32x4 __attribute__((ext_vector_type(4)));

__device__ inline short f2bf(float f) {
    unsigned u = __float_as_uint(f);
    u += 0x7fffu + ((u >> 16) & 1u);     // round-to-nearest-even
    return (short)(u >> 16);
}

// ---------------------------------------------------------------------------
// Prep 1: elementwise fp32 -> bf16 convert of W1 and W2.
// grid 256 x 256; thread handles 4 elems of each matrix (float4 -> short4).
// ---------------------------------------------------------------------------
__global__ __launch_bounds__(256)
void esa_prep_convert(const float* __restrict__ W1, const float* __restrict__ W2,
                      short* __restrict__ W1b, short* __restrict__ W2b) {
    const int gid = blockIdx.x * 256 + threadIdx.x;   // 0..65535
    const int i4 = gid * 4;
    const float4 a = *(const float4*)(W1 + i4);
    const float4 b = *(const float4*)(W2 + i4);
    short4v sa = {f2bf(a.x), f2bf(a.y), f2bf(a.z), f2bf(a.w)};
    short4v sb = {f2bf(b.x), f2bf(b.y), f2bf(b.z), f2bf(b.w)};
    *(short4v*)(W1b + i4) = sa;
    *(short4v*)(W2b + i4) = sb;
}

// ---------------------------------------------------------------------------
// Prep 1b: b12 = W2 @ b1 + b2.  1 block x 512 threads, b1 staged in LDS.
// ---------------------------------------------------------------------------
__global__ __launch_bounds__(512)
void esa_prep_b12(const float* __restrict__ W2, const float* __restrict__ b1,
                  const float* __restrict__ b2, float* __restrict__ b12) {
    __shared__ float b1s[512];
    b1s[threadIdx.x] = b1[threadIdx.x];
    __syncthreads();
    const int i = threadIdx.x;
    float acc = b2[i];
    const float* row = W2 + (size_t)i * 512;
#pragma unroll 4
    for (int k = 0; k < 512; k += 4) {
        const float4 w = *(const float4*)(row + k);
        acc += w.x * b1s[k] + w.y * b1s[k + 1] + w.z * b1s[k + 2] + w.w * b1s[k + 3];
    }
    b12[i] = acc;
}

// ---------------------------------------------------------------------------
// Prep 2: W12b[n,k] = sum_j W2b[n,j] * W1b[j,k]  via MFMA (fp32 accumulate).
// grid 64 (8x8 tiles of 64x64), 256 threads. Wave w owns 16 k-cols.
// A-frag = rows of W2b (coalesced short8); B-frag = cols of W1b (strided).
// ---------------------------------------------------------------------------
__global__ __launch_bounds__(256)
void esa_prep_w12(const short* __restrict__ W1b, const short* __restrict__ W2b,
                  short* __restrict__ W12b) {
    const int n0 = (blockIdx.x >> 3) * 64;
    const int k0b = (blockIdx.x & 7) * 64;
    const int wave = threadIdx.x >> 6;
    const int lane = threadIdx.x & 63;
    const int quad = lane >> 4;
    const int l16 = lane & 15;
    const int kcol = k0b + wave * 16 + l16;

    f32x4 acc[4];
#pragma unroll
    for (int mt = 0; mt < 4; ++mt) acc[mt] = (f32x4)0.0f;

    for (int j0 = 0; j0 < 512; j0 += 32) {
        short8 bfr;
#pragma unroll
        for (int jj = 0; jj < 8; ++jj)
            bfr[jj] = W1b[(size_t)(j0 + quad * 8 + jj) * 512 + kcol];
        short8 afr[4];
#pragma unroll
        for (int mt = 0; mt < 4; ++mt)
            afr[mt] = *(const short8*)(W2b + (size_t)(n0 + mt * 16 + l16) * 512 +
                                       j0 + quad * 8);
#pragma unroll
        for (int mt = 0; mt < 4; ++mt)
            acc[mt] = __builtin_amdgcn_mfma_f32_16x16x32_bf16(afr[mt], bfr,
                                                              acc[mt], 0, 0, 0);
    }
    // C/D layout: col = lane&15, row = quad*4 + r  (m89-verified)
#pragma unroll
    for (int mt = 0; mt < 4; ++mt)
#pragma unroll
        for (int r = 0; r < 4; ++r)
            W12b[(size_t)(n0 + mt * 16 + quad * 4 + r) * 512 + kcol] =
                f2bf(acc[mt][r]);
}

// ---------------------------------------------------------------------------
// Prep 3: per-batch offsets via binary search on sorted data_batch, then
// batch-boundary-aligned 64-node chunk entries {batch, start, valid}.
// ---------------------------------------------------------------------------
__global__ __launch_bounds__(256)
void esa_prep_entries(const int* __restrict__ db, int T, int B,
                      int4* __restrict__ entries, int maxent) {
    __shared__ int off[513];
    __shared__ int nch[512];
    __shared__ int scan[513];
    for (int t = threadIdx.x; t <= B; t += 256) {
        if (t == B) {
            off[t] = T;
        } else {
            int lo = 0, hi = T;
            while (lo < hi) {
                int mid = (lo + hi) >> 1;
                if (db[mid] < t) lo = mid + 1; else hi = mid;
            }
            off[t] = lo;
        }
    }
    __syncthreads();
    for (int t = threadIdx.x; t < B; t += 256)
        nch[t] = (off[t + 1] - off[t] + 63) >> 6;
    __syncthreads();
    if (threadIdx.x == 0) {
        int s = 0;
        for (int i = 0; i < B; ++i) { scan[i] = s; s += nch[i]; }
        scan[B] = s;
    }
    __syncthreads();
    for (int t = threadIdx.x; t < B; t += 256) {
        int cnt = off[t + 1] - off[t];
        for (int j = 0; j < nch[t]; ++j) {
            int v = cnt - j * 64;
            if (v > 64) v = 64;
            entries[scan[t] + j] = make_int4(t, off[t] + j * 64, v, 0);
        }
    }
    int total = scan[B];
    for (int i = total + threadIdx.x; i < maxent; i += 256)
        entries[i] = make_int4(0, 0, 0, 0);
}

// ---------------------------------------------------------------------------
// Main fused kernel: one block = 64 nodes of one batch, 512 threads (8 waves).
// 2 blocks/CU (LDS 66.5KB) -> 16 waves/CU. __launch_bounds__(512,4) caps
// VGPR at 128 so 4 waves/SIMD are resident.
// Phase 1: LayerNorm -> y bf16 in LDS (8 rows per wave).
// Phase 2: dual GEMM (cap via W1b, feat via W12b), wave owns 64 cols,
//          B-fragments software-pipelined one k-step ahead (L2 ~200cyc).
// Epilogue: e=exp(feat); per-column sum(e), sum(e*cap) over 64 rows; atomics.
// ---------------------------------------------------------------------------
#define LSTRIDE 520

__global__ __launch_bounds__(512, 4)
void esa_fused(const float* __restrict__ x, const float* __restrict__ gamma,
               const float* __restrict__ beta, const short* __restrict__ W1b,
               const short* __restrict__ W12b, const float* __restrict__ b1,
               const float* __restrict__ b12, const int4* __restrict__ entries,
               float* __restrict__ num, float* __restrict__ den) {
    __shared__ short ylds[64 * LSTRIDE];   // 66,560 B -> 2 blocks/CU
    const int4 e = entries[blockIdx.x];
    const int bat = e.x, start = e.y, valid = e.z;
    if (valid <= 0) return;

    const int tid = threadIdx.x;
    const int wave = tid >> 6;          // 0..7
    const int lane = tid & 63;
    const int quad = lane >> 4;
    const int l16 = lane & 15;

    // ---- Phase 1: LayerNorm. wave handles rows wave*8 .. +7, lane owns 8 cols
    const float4 g0 = *(const float4*)(gamma + lane * 8);
    const float4 g1 = *(const float4*)(gamma + lane * 8 + 4);
    const float4 be0 = *(const float4*)(beta + lane * 8);
    const float4 be1 = *(const float4*)(beta + lane * 8 + 4);

    for (int r = 0; r < 8; ++r) {
        const int m = wave * 8 + r;
        short8 outv = {0, 0, 0, 0, 0, 0, 0, 0};
        if (m < valid) {   // wave-uniform branch
            const float* xr = x + (size_t)(start + m) * 512 + lane * 8;
            const float4 a = *(const float4*)xr;
            const float4 b = *(const float4*)(xr + 4);
            float s = a.x + a.y + a.z + a.w + b.x + b.y + b.z + b.w;
            float ss = a.x * a.x + a.y * a.y + a.z * a.z + a.w * a.w +
                       b.x * b.x + b.y * b.y + b.z * b.z + b.w * b.w;
#pragma unroll
            for (int o = 1; o <= 32; o <<= 1) {
                s += __shfl_xor(s, o);
                ss += __shfl_xor(ss, o);
            }
            const float mu = s * (1.0f / 512.0f);
            const float var = ss * (1.0f / 512.0f) - mu * mu;
            const float rstd = rsqrtf(var + 1e-5f);
            outv[0] = f2bf((a.x - mu) * rstd * g0.x + be0.x);
            outv[1] = f2bf((a.y - mu) * rstd * g0.y + be0.y);
            outv[2] = f2bf((a.z - mu) * rstd * g0.z + be0.z);
            outv[3] = f2bf((a.w - mu) * rstd * g0.w + be0.w);
            outv[4] = f2bf((b.x - mu) * rstd * g1.x + be1.x);
            outv[5] = f2bf((b.y - mu) * rstd * g1.y + be1.y);
            outv[6] = f2bf((b.z - mu) * rstd * g1.z + be1.z);
            outv[7] = f2bf((b.w - mu) * rstd * g1.w + be1.w);
        }
        *(short8*)&ylds[m * LSTRIDE + lane * 8] = outv;
    }
    __syncthreads();

    // ---- Phase 2: dual GEMM + epilogue. Wave owns cols [wave*64, +64).
    const int kbase = quad * 8;
    const short* ap = &ylds[l16 * LSTRIDE + kbase];

    for (int grp = 0; grp < 2; ++grp) {
        const int n0 = wave * 64 + grp * 32;
        f32x4 acc_c[2][4], acc_f[2][4];
#pragma unroll
        for (int nt = 0; nt < 2; ++nt)
#pragma unroll
            for (int mt = 0; mt < 4; ++mt) {
                acc_c[nt][mt] = (f32x4)0.0f;
                acc_f[nt][mt] = (f32x4)0.0f;
            }
        const short* w1p0 = W1b + (size_t)(n0 + l16) * 512 + kbase;
        const short* w1p1 = W1b + (size_t)(n0 + 16 + l16) * 512 + kbase;
        const short* w2p0 = W12b + (size_t)(n0 + l16) * 512 + kbase;
        const short* w2p1 = W12b + (size_t)(n0 + 16 + l16) * 512 + kbase;

        // software pipeline: B-fragments loaded one k-step ahead
        short8 b10 = *(const short8*)(w1p0);
        short8 b11 = *(const short8*)(w1p1);
        short8 b20 = *(const short8*)(w2p0);
        short8 b21 = *(const short8*)(w2p1);

#pragma unroll 2
        for (int k0 = 0; k0 < 16; ++k0) {
            short8 afr[4];
#pragma unroll
            for (int mt = 0; mt < 4; ++mt)
                afr[mt] = *(const short8*)(ap + mt * 16 * LSTRIDE + k0 * 32);
            const int kn = (k0 < 15 ? k0 + 1 : k0) * 32;
            const short8 nb10 = *(const short8*)(w1p0 + kn);
            const short8 nb11 = *(const short8*)(w1p1 + kn);
            const short8 nb20 = *(const short8*)(w2p0 + kn);
            const short8 nb21 = *(const short8*)(w2p1 + kn);
#pragma unroll
            for (int mt = 0; mt < 4; ++mt) {
                acc_c[0][mt] = __builtin_amdgcn_mfma_f32_16x16x32_bf16(
                    afr[mt], b10, acc_c[0][mt], 0, 0, 0);
                acc_c[1][mt] = __builtin_amdgcn_mfma_f32_16x16x32_bf16(
                    afr[mt], b11, acc_c[1][mt], 0, 0, 0);
                acc_f[0][mt] = __builtin_amdgcn_mfma_f32_16x16x32_bf16(
                    afr[mt], b20, acc_f[0][mt], 0, 0, 0);
                acc_f[1][mt] = __builtin_amdgcn_mfma_f32_16x16x32_bf16(
                    afr[mt], b21, acc_f[1][mt], 0, 0, 0);
            }
            b10 = nb10; b11 = nb11; b20 = nb20; b21 = nb21;
        }
        // Epilogue: C/D layout col=lane&15, row=quad*4+reg (m89-verified)
#pragma unroll
        for (int nt = 0; nt < 2; ++nt) {
            const int n = n0 + nt * 16 + l16;
            const float bb1 = b1[n];
            const float bb2 = b12[n];
            float se = 0.0f, sec = 0.0f;
#pragma unroll
            for (int mt = 0; mt < 4; ++mt) {
#pragma unroll
                for (int r2 = 0; r2 < 4; ++r2) {
                    const int m = mt * 16 + quad * 4 + r2;
                    const float cap = acc_c[nt][mt][r2] + bb1;
                    const float ft = acc_f[nt][mt][r2] + bb2;
                    if (m < valid) {
                        const float ev = __expf(ft);
                        se += ev;
                        sec += ev * cap;
                    }
                }
            }
            se += __shfl_xor(se, 16);
            se += __shfl_xor(se, 32);
            sec += __shfl_xor(sec, 16);
            sec += __shfl_xor(sec, 32);
            if (quad == 0) atomicAdd(&den[(size_t)bat * 512 + n], se);
            else if (quad == 1) atomicAdd(&num[(size_t)bat * 512 + n], sec);
        }
    }
}

__global__ __launch_bounds__(256)
void esa_finalize(const float* __restrict__ num, const float* __restrict__ den,
                  float* __restrict__ out, int n) {
    const int i = blockIdx.x * 256 + threadIdx.x;
    if (i < n) {
        const float d = den[i];
        out[i] = d > 0.0f ? num[i] / d : 0.0f;
    }
}

extern "C" void kernel_launch(void* const* d_in, const int* in_sizes, int n_in,
                              void* d_out, int out_size, void* d_ws, size_t ws_size,
                              hipStream_t stream) {
    const float* x = (const float*)d_in[0];
    const int* db = (const int*)d_in[1];
    // d_in[2] = max_nodes (unused: chunking derived from actual counts)
    const float* gamma = (const float*)d_in[3];
    const float* beta = (const float*)d_in[4];
    const float* W1 = (const float*)d_in[5];
    const float* b1 = (const float*)d_in[6];
    const float* W2 = (const float*)d_in[7];
    const float* b2 = (const float*)d_in[8];
    float* out = (float*)d_out;

    const int C = in_sizes[3];        // 512
    const int D = in_sizes[6];        // 512
    const int T = in_sizes[0] / C;    // 131072
    const int B = out_size / D;       // 128
    const int maxent = B + (T + 63) / 64;

    char* ws = (char*)d_ws;
    short* W1b = (short*)(ws);                      // 512 KB
    short* W12b = (short*)(ws + 524288);            // 512 KB
    short* W2b = (short*)(ws + 1048576);            // 512 KB
    float* b12 = (float*)(ws + 1572864);            // 2 KB
    int4* entries = (int4*)(ws + 1574912);          // maxent*16
    size_t numoff = (1574912 + (size_t)maxent * 16 + 255) & ~(size_t)255;
    float* num = (float*)(ws + numoff);             // B*D*4
    float* den = (float*)(ws + numoff + (size_t)B * D * 4);

    hipMemsetAsync(num, 0, (size_t)B * D * 8, stream);
    esa_prep_convert<<<256, 256, 0, stream>>>(W1, W2, W1b, W2b);
    esa_prep_b12<<<1, 512, 0, stream>>>(W2, b1, b2, b12);
    esa_prep_w12<<<64, 256, 0, stream>>>(W1b, W2b, W12b);
    esa_prep_entries<<<1, 256, 0, stream>>>(db, T, B, entries, maxent);
    esa_fused<<<maxent, 512, 0, stream>>>(x, gamma, beta, W1b, W12b, b1, b12,
                                          entries, num, den);
    esa_finalize<<<(B * D + 255) / 256, 256, 0, stream>>>(num, den, out, B * D);
}

// Round 4
// 606.860 us; speedup vs baseline: 1.1862x; 1.0819x over previous
//
#include <hip/hip_runtime.h>
#include <hip/hip_bf16.h>

// ESA_SMILES fused pipeline for MI355X (gfx950).
// Identity: cap = LN(x)@W1^T+b1 ; feat = cap@W2^T+b2 = LN(x)@(W2W1)^T+(W2b1+b2)
// -> both cap and feat are GEMMs from the same y = LN(x); softmax-weighted
// reduction happens in-register (fragments element-aligned).
// out[b,d] = sum_n exp(feat[n,d])*cap[n,d] / sum_n exp(feat[n,d])

typedef short short8 __attribute__((ext_vector_type(8)));   // 8 x bf16
typedef short short4v __attribute__((ext_vector_type(4)));
typedef float f32x4 __attribute__((ext_vector_type(4)));

__device__ inline short f2bf(float f) {
    unsigned u = __float_as_uint(f);
    u += 0x7fffu + ((u >> 16) & 1u);     // round-to-nearest-even
    return (short)(u >> 16);
}

// ---------------------------------------------------------------------------
// prep_all: ONE dispatch, role-split blocks (512 threads each):
//   blocks 0..63    : W12b = bf16(W2) @ bf16(W1) via MFMA (fp32 read+convert)
//   blocks 64..191  : W1 fp32 -> bf16 (W1b)
//   blocks 192..195 : b12 = W2@b1 + b2 (4 blocks x 128 rows, 4 thr/row)
//   block  196      : entries (binary search on sorted data_batch)
//   blocks 197..228 : zero num/den
// ---------------------------------------------------------------------------
#define PREP_GRID 229

__global__ __launch_bounds__(512)
void esa_prep_all(const float* __restrict__ W1, const float* __restrict__ W2,
                  const float* __restrict__ b1, const float* __restrict__ b2,
                  const int* __restrict__ db, int T, int B,
                  short* __restrict__ W1b, short* __restrict__ W12b,
                  float* __restrict__ b12, int4* __restrict__ entries, int maxent,
                  float* __restrict__ numden) {
    __shared__ int off[513];
    __shared__ int nch[512];
    __shared__ int scan[513];
    const int bid = blockIdx.x;
    const int tid = threadIdx.x;

    if (bid < 64) {
        // ---- W12 tile (64x64) via MFMA, converting fp32->bf16 on the fly
        const int ti = bid >> 3, tj = bid & 7;
        const int wave = tid >> 6;          // 0..7
        const int lane = tid & 63;
        const int quad = lane >> 4;
        const int l16 = lane & 15;
        const int mhalf = wave >> 2;        // rows half (m-tiles 0-1 or 2-3)
        const int kq = wave & 3;
        const int kcol = tj * 64 + kq * 16 + l16;

        f32x4 acc[2];
        acc[0] = (f32x4)0.0f; acc[1] = (f32x4)0.0f;
        for (int j0 = 0; j0 < 512; j0 += 32) {
            short8 bfr;
#pragma unroll
            for (int jj = 0; jj < 8; ++jj)
                bfr[jj] = f2bf(W1[(size_t)(j0 + quad * 8 + jj) * 512 + kcol]);
#pragma unroll
            for (int mt = 0; mt < 2; ++mt) {
                const float* ar = W2 + (size_t)(ti * 64 + (mhalf * 2 + mt) * 16 + l16) * 512 +
                                  j0 + quad * 8;
                const float4 a0 = *(const float4*)ar;
                const float4 a1 = *(const float4*)(ar + 4);
                short8 afr = {f2bf(a0.x), f2bf(a0.y), f2bf(a0.z), f2bf(a0.w),
                              f2bf(a1.x), f2bf(a1.y), f2bf(a1.z), f2bf(a1.w)};
                acc[mt] = __builtin_amdgcn_mfma_f32_16x16x32_bf16(afr, bfr,
                                                                  acc[mt], 0, 0, 0);
            }
        }
        // C/D layout: col = lane&15, row = quad*4 + r
#pragma unroll
        for (int mt = 0; mt < 2; ++mt)
#pragma unroll
            for (int r = 0; r < 4; ++r)
                W12b[(size_t)(ti * 64 + (mhalf * 2 + mt) * 16 + quad * 4 + r) * 512 +
                     kcol] = f2bf(acc[mt][r]);
    } else if (bid < 192) {
        // ---- W1 -> bf16
        const int gid = (bid - 64) * 512 + tid;
        const int i4 = gid * 4;
        const float4 a = *(const float4*)(W1 + i4);
        short4v sa = {f2bf(a.x), f2bf(a.y), f2bf(a.z), f2bf(a.w)};
        *(short4v*)(W1b + i4) = sa;
    } else if (bid < 196) {
        // ---- b12 = W2@b1 + b2 : 4 blocks x 128 rows, 4 threads per row
        const int row = (bid - 192) * 128 + (tid >> 2);
        const int part = tid & 3;
        const float* wr = W2 + (size_t)row * 512;
        float acc = 0.0f;
#pragma unroll 4
        for (int i = 0; i < 32; ++i) {
            const float4 w = *(const float4*)(wr + (i * 4 + part) * 4);
            const float4 bb = *(const float4*)(b1 + (i * 4 + part) * 4);
            acc += w.x * bb.x + w.y * bb.y + w.z * bb.z + w.w * bb.w;
        }
        acc += __shfl_xor(acc, 1);
        acc += __shfl_xor(acc, 2);
        if (part == 0) b12[row] = acc + b2[row];
    } else if (bid == 196) {
        // ---- entries
        for (int t = tid; t <= B; t += 512) {
            if (t == B) {
                off[t] = T;
            } else {
                int lo = 0, hi = T;
                while (lo < hi) {
                    int mid = (lo + hi) >> 1;
                    if (db[mid] < t) lo = mid + 1; else hi = mid;
                }
                off[t] = lo;
            }
        }
        __syncthreads();
        for (int t = tid; t < B; t += 512)
            nch[t] = (off[t + 1] - off[t] + 63) >> 6;
        __syncthreads();
        if (tid == 0) {
            int s = 0;
            for (int i = 0; i < B; ++i) { scan[i] = s; s += nch[i]; }
            scan[B] = s;
        }
        __syncthreads();
        for (int t = tid; t < B; t += 512) {
            int cnt = off[t + 1] - off[t];
            for (int j = 0; j < nch[t]; ++j) {
                int v = cnt - j * 64;
                if (v > 64) v = 64;
                entries[scan[t] + j] = make_int4(t, off[t] + j * 64, v, 0);
            }
        }
        int total = scan[B];
        for (int i = total + tid; i < maxent; i += 512)
            entries[i] = make_int4(0, 0, 0, 0);
    } else {
        // ---- zero num/den (2*B*512 floats = 131072)
        const int idx = (bid - 197) * 512 + tid;   // 0..16383
        float4 z = {0.0f, 0.0f, 0.0f, 0.0f};
        *(float4*)(numden + (size_t)idx * 8) = z;
        *(float4*)(numden + (size_t)idx * 8 + 4) = z;
    }
}

// ---------------------------------------------------------------------------
// Main fused kernel: one block = 64 nodes of one batch, 512 threads (8 waves),
// 2 blocks/CU (LDS exactly 64KB) -> 16 waves/CU.
// Phase 1: LayerNorm, branch-free (row index clamped; rows >= valid produce
//   garbage that the epilogue masks out), 4-row ILP groups, XOR-swizzled
//   bf16 store to LDS (conflict-free).
// Phase 2: dual GEMM (cap via W1b, feat via W12b); wave owns 64 cols; A-frags
//   from swizzled LDS (conflict-free ds_read_b128), B-frags from L2.
// Epilogue: e=exp(feat); per-column sum(e), sum(e*cap); 2 atomics/col.
// ---------------------------------------------------------------------------
__global__ __launch_bounds__(512, 4)
void esa_fused(const float* __restrict__ x, const float* __restrict__ gamma,
               const float* __restrict__ beta, const short* __restrict__ W1b,
               const short* __restrict__ W12b, const float* __restrict__ b1,
               const float* __restrict__ b12, const int4* __restrict__ entries,
               float* __restrict__ num, float* __restrict__ den) {
    __shared__ short ylds[64 * 512];   // 65,536 B exactly -> 2 blocks/CU
    const int4 e = entries[blockIdx.x];
    const int bat = e.x, start = e.y, valid = e.z;
    if (valid <= 0) return;

    const int tid = threadIdx.x;
    const int wave = tid >> 6;          // 0..7
    const int lane = tid & 63;
    const int quad = lane >> 4;
    const int l16 = lane & 15;

    // ---- Phase 1: LayerNorm, rows wave*8..+7, lane owns 8 cols. Branch-free.
    const float4 g0 = *(const float4*)(gamma + lane * 8);
    const float4 g1 = *(const float4*)(gamma + lane * 8 + 4);
    const float4 be0 = *(const float4*)(beta + lane * 8);
    const float4 be1 = *(const float4*)(beta + lane * 8 + 4);

#pragma unroll
    for (int g = 0; g < 2; ++g) {               // two ILP groups of 4 rows
        float4 ra[4], rb[4];
        float s[4], ss[4];
#pragma unroll
        for (int r = 0; r < 4; ++r) {
            const int m = wave * 8 + g * 4 + r;
            const int mc = m < valid ? m : valid - 1;   // clamp: always in-batch
            const float* xr = x + (size_t)(start + mc) * 512 + lane * 8;
            ra[r] = *(const float4*)xr;
            rb[r] = *(const float4*)(xr + 4);
        }
#pragma unroll
        for (int r = 0; r < 4; ++r) {
            s[r] = ra[r].x + ra[r].y + ra[r].z + ra[r].w +
                   rb[r].x + rb[r].y + rb[r].z + rb[r].w;
            ss[r] = ra[r].x * ra[r].x + ra[r].y * ra[r].y + ra[r].z * ra[r].z +
                    ra[r].w * ra[r].w + rb[r].x * rb[r].x + rb[r].y * rb[r].y +
                    rb[r].z * rb[r].z + rb[r].w * rb[r].w;
        }
#pragma unroll
        for (int o = 1; o <= 32; o <<= 1) {     // 4 interleaved chains
#pragma unroll
            for (int r = 0; r < 4; ++r) {
                s[r] += __shfl_xor(s[r], o);
                ss[r] += __shfl_xor(ss[r], o);
            }
        }
#pragma unroll
        for (int r = 0; r < 4; ++r) {
            const int m = wave * 8 + g * 4 + r;
            const float mu = s[r] * (1.0f / 512.0f);
            const float var = ss[r] * (1.0f / 512.0f) - mu * mu;
            const float rstd = rsqrtf(var + 1e-5f);
            short8 outv;
            outv[0] = f2bf((ra[r].x - mu) * rstd * g0.x + be0.x);
            outv[1] = f2bf((ra[r].y - mu) * rstd * g0.y + be0.y);
            outv[2] = f2bf((ra[r].z - mu) * rstd * g0.z + be0.z);
            outv[3] = f2bf((ra[r].w - mu) * rstd * g0.w + be0.w);
            outv[4] = f2bf((rb[r].x - mu) * rstd * g1.x + be1.x);
            outv[5] = f2bf((rb[r].y - mu) * rstd * g1.y + be1.y);
            outv[6] = f2bf((rb[r].z - mu) * rstd * g1.z + be1.z);
            outv[7] = f2bf((rb[r].w - mu) * rstd * g1.w + be1.w);
            // XOR swizzle: column-block lane stored at lane ^ (m&7)
            *(short8*)&ylds[m * 512 + ((lane ^ (m & 7)) * 8)] = outv;
        }
    }
    __syncthreads();

    // ---- Phase 2: dual GEMM + epilogue. Wave owns cols [wave*64, +64).
    const int xr7 = l16 & 7;
    const short* abase = ylds + l16 * 512;

    for (int grp = 0; grp < 2; ++grp) {
        const int n0 = wave * 64 + grp * 32;
        f32x4 acc_c[2][4], acc_f[2][4];
#pragma unroll
        for (int nt = 0; nt < 2; ++nt)
#pragma unroll
            for (int mt = 0; mt < 4; ++mt) {
                acc_c[nt][mt] = (f32x4)0.0f;
                acc_f[nt][mt] = (f32x4)0.0f;
            }
        const short* w1p0 = W1b + (size_t)(n0 + l16) * 512 + quad * 8;
        const short* w1p1 = w1p0 + 16 * 512;
        const short* w2p0 = W12b + (size_t)(n0 + l16) * 512 + quad * 8;
        const short* w2p1 = w2p0 + 16 * 512;

#pragma unroll 2
        for (int k0 = 0; k0 < 16; ++k0) {
            // swizzled A-frag address: column block (4k0+quad) ^ (l16&7)
            const int blk = ((k0 << 2) | quad) ^ xr7;
            const short* ap = abase + blk * 8;
            short8 afr[4];
#pragma unroll
            for (int mt = 0; mt < 4; ++mt)
                afr[mt] = *(const short8*)(ap + mt * 16 * 512);
            const short8 b10 = *(const short8*)(w1p0 + k0 * 32);
            const short8 b11 = *(const short8*)(w1p1 + k0 * 32);
            const short8 b20 = *(const short8*)(w2p0 + k0 * 32);
            const short8 b21 = *(const short8*)(w2p1 + k0 * 32);
#pragma unroll
            for (int mt = 0; mt < 4; ++mt) {
                acc_c[0][mt] = __builtin_amdgcn_mfma_f32_16x16x32_bf16(
                    afr[mt], b10, acc_c[0][mt], 0, 0, 0);
                acc_c[1][mt] = __builtin_amdgcn_mfma_f32_16x16x32_bf16(
                    afr[mt], b11, acc_c[1][mt], 0, 0, 0);
                acc_f[0][mt] = __builtin_amdgcn_mfma_f32_16x16x32_bf16(
                    afr[mt], b20, acc_f[0][mt], 0, 0, 0);
                acc_f[1][mt] = __builtin_amdgcn_mfma_f32_16x16x32_bf16(
                    afr[mt], b21, acc_f[1][mt], 0, 0, 0);
            }
        }
        // Epilogue: C/D layout col=lane&15, row=quad*4+reg (m89-verified)
#pragma unroll
        for (int nt = 0; nt < 2; ++nt) {
            const int n = n0 + nt * 16 + l16;
            const float bb1 = b1[n];
            const float bb2 = b12[n];
            float se = 0.0f, sec = 0.0f;
#pragma unroll
            for (int mt = 0; mt < 4; ++mt) {
#pragma unroll
                for (int r2 = 0; r2 < 4; ++r2) {
                    const int m = mt * 16 + quad * 4 + r2;
                    const float cap = acc_c[nt][mt][r2] + bb1;
                    const float ft = acc_f[nt][mt][r2] + bb2;
                    if (m < valid) {
                        const float ev = __expf(ft);
                        se += ev;
                        sec += ev * cap;
                    }
                }
            }
            se += __shfl_xor(se, 16);
            se += __shfl_xor(se, 32);
            sec += __shfl_xor(sec, 16);
            sec += __shfl_xor(sec, 32);
            if (quad == 0) atomicAdd(&den[(size_t)bat * 512 + n], se);
            else if (quad == 1) atomicAdd(&num[(size_t)bat * 512 + n], sec);
        }
    }
}

__global__ __launch_bounds__(256)
void esa_finalize(const float* __restrict__ num, const float* __restrict__ den,
                  float* __restrict__ out, int n) {
    const int i = blockIdx.x * 256 + threadIdx.x;
    if (i < n) {
        const float d = den[i];
        out[i] = d > 0.0f ? num[i] / d : 0.0f;
    }
}

extern "C" void kernel_launch(void* const* d_in, const int* in_sizes, int n_in,
                              void* d_out, int out_size, void* d_ws, size_t ws_size,
                              hipStream_t stream) {
    const float* x = (const float*)d_in[0];
    const int* db = (const int*)d_in[1];
    // d_in[2] = max_nodes (unused: chunking derived from actual counts)
    const float* gamma = (const float*)d_in[3];
    const float* beta = (const float*)d_in[4];
    const float* W1 = (const float*)d_in[5];
    const float* b1 = (const float*)d_in[6];
    const float* W2 = (const float*)d_in[7];
    const float* b2 = (const float*)d_in[8];
    float* out = (float*)d_out;

    const int C = in_sizes[3];        // 512
    const int D = in_sizes[6];        // 512
    const int T = in_sizes[0] / C;    // 131072
    const int B = out_size / D;       // 128
    const int maxent = B + (T + 63) / 64;   // 2176

    char* ws = (char*)d_ws;
    short* W1b = (short*)(ws);                      // 512 KB
    short* W12b = (short*)(ws + 524288);            // 512 KB
    float* b12 = (float*)(ws + 1048576);            // 2 KB
    int4* entries = (int4*)(ws + 1050624);          // maxent*16
    size_t numoff = (1050624 + (size_t)maxent * 16 + 255) & ~(size_t)255;
    float* num = (float*)(ws + numoff);             // B*D*4
    float* den = (float*)(ws + numoff + (size_t)B * D * 4);

    esa_prep_all<<<PREP_GRID, 512, 0, stream>>>(W1, W2, b1, b2, db, T, B,
                                                W1b, W12b, b12, entries, maxent,
                                                num);
    esa_fused<<<maxent, 512, 0, stream>>>(x, gamma, beta, W1b, W12b, b1, b12,
                                          entries, num, den);
    esa_finalize<<<(B * D + 255) / 256, 256, 0, stream>>>(num, den, out, B * D);
}

// Round 5
// 469.733 us; speedup vs baseline: 1.5325x; 1.2919x over previous
//
#include <hip/hip_runtime.h>
#include <hip/hip_bf16.h>

// ESA_SMILES fused pipeline for MI355X (gfx950).
// Identity: cap = LN(x)@W1^T+b1 ; feat = cap@W2^T+b2 = LN(x)@(W2W1)^T+(W2b1+b2)
// -> both cap and feat are GEMMs from the same y = LN(x); softmax-weighted
// reduction happens in-register (fragments element-aligned).
// out[b,d] = sum_n exp(feat[n,d])*cap[n,d] / sum_n exp(feat[n,d])
//
// R5 change: weights stored in PACKED MFMA B-fragment order
//   W*p[t][k0][lane][j]  (t = n>>4 [32], k0 = k>>5 [16], lane = ((k>>3)&3)*16
//                         + (n&15) [64], j = k&7 [8])
// so the fused K-loop's B-frag load is lane-contiguous (1KB/instr, coalesced)
// instead of a 16-line 1KB-strided gather.

typedef short short8 __attribute__((ext_vector_type(8)));   // 8 x bf16
typedef short short4v __attribute__((ext_vector_type(4)));
typedef float f32x4 __attribute__((ext_vector_type(4)));

__device__ inline short f2bf(float f) {
    unsigned u = __float_as_uint(f);
    u += 0x7fffu + ((u >> 16) & 1u);     // round-to-nearest-even
    return (short)(u >> 16);
}

// packed offset for element (n, k) of a 512x512 weight matrix
__device__ inline size_t packed_off(int n, int k) {
    const int t = n >> 4, l16 = n & 15;
    const int k0 = k >> 5, quad = (k >> 3) & 3, j = k & 7;
    return ((size_t)((t * 16 + k0) * 64 + quad * 16 + l16)) * 8 + j;
}

// ---------------------------------------------------------------------------
// prep_all: ONE dispatch, role-split blocks (512 threads each):
//   blocks 0..63    : W12p = bf16(W2) @ bf16(W1) via MFMA -> packed layout
//   blocks 64..191  : W1 fp32 -> bf16, packed layout (W1p)
//   blocks 192..195 : b12 = W2@b1 + b2 (4 blocks x 128 rows, 4 thr/row)
//   block  196      : entries (binary search on sorted data_batch)
//   blocks 197..228 : zero num/den
// ---------------------------------------------------------------------------
#define PREP_GRID 229

__global__ __launch_bounds__(512)
void esa_prep_all(const float* __restrict__ W1, const float* __restrict__ W2,
                  const float* __restrict__ b1, const float* __restrict__ b2,
                  const int* __restrict__ db, int T, int B,
                  short* __restrict__ W1p, short* __restrict__ W12p,
                  float* __restrict__ b12, int4* __restrict__ entries, int maxent,
                  float* __restrict__ numden) {
    __shared__ int off[513];
    __shared__ int nch[512];
    __shared__ int scan[513];
    const int bid = blockIdx.x;
    const int tid = threadIdx.x;

    if (bid < 64) {
        // ---- W12 tile (64x64) via MFMA, converting fp32->bf16 on the fly
        const int ti = bid >> 3, tj = bid & 7;
        const int wave = tid >> 6;          // 0..7
        const int lane = tid & 63;
        const int quad = lane >> 4;
        const int l16 = lane & 15;
        const int mhalf = wave >> 2;        // rows half (m-tiles 0-1 or 2-3)
        const int kq = wave & 3;
        const int kcol = tj * 64 + kq * 16 + l16;

        f32x4 acc[2];
        acc[0] = (f32x4)0.0f; acc[1] = (f32x4)0.0f;
        for (int j0 = 0; j0 < 512; j0 += 32) {
            short8 bfr;
#pragma unroll
            for (int jj = 0; jj < 8; ++jj)
                bfr[jj] = f2bf(W1[(size_t)(j0 + quad * 8 + jj) * 512 + kcol]);
#pragma unroll
            for (int mt = 0; mt < 2; ++mt) {
                const float* ar = W2 + (size_t)(ti * 64 + (mhalf * 2 + mt) * 16 + l16) * 512 +
                                  j0 + quad * 8;
                const float4 a0 = *(const float4*)ar;
                const float4 a1 = *(const float4*)(ar + 4);
                short8 afr = {f2bf(a0.x), f2bf(a0.y), f2bf(a0.z), f2bf(a0.w),
                              f2bf(a1.x), f2bf(a1.y), f2bf(a1.z), f2bf(a1.w)};
                acc[mt] = __builtin_amdgcn_mfma_f32_16x16x32_bf16(afr, bfr,
                                                                  acc[mt], 0, 0, 0);
            }
        }
        // C/D layout: col(k) = lane&15, row(n) = quad*4 + r -> packed store
#pragma unroll
        for (int mt = 0; mt < 2; ++mt)
#pragma unroll
            for (int r = 0; r < 4; ++r) {
                const int n = ti * 64 + (mhalf * 2 + mt) * 16 + quad * 4 + r;
                W12p[packed_off(n, kcol)] = f2bf(acc[mt][r]);
            }
    } else if (bid < 192) {
        // ---- W1 -> bf16, packed. 4 consecutive k share a packed short4 slot.
        const int gid = (bid - 64) * 512 + tid;
        const int i4 = gid * 4;
        const int n = i4 >> 9, k = i4 & 511;
        const float4 a = *(const float4*)(W1 + i4);
        short4v sa = {f2bf(a.x), f2bf(a.y), f2bf(a.z), f2bf(a.w)};
        *(short4v*)(W1p + packed_off(n, k)) = sa;
    } else if (bid < 196) {
        // ---- b12 = W2@b1 + b2 : 4 blocks x 128 rows, 4 threads per row
        const int row = (bid - 192) * 128 + (tid >> 2);
        const int part = tid & 3;
        const float* wr = W2 + (size_t)row * 512;
        float acc = 0.0f;
#pragma unroll 4
        for (int i = 0; i < 32; ++i) {
            const float4 w = *(const float4*)(wr + (i * 4 + part) * 4);
            const float4 bb = *(const float4*)(b1 + (i * 4 + part) * 4);
            acc += w.x * bb.x + w.y * bb.y + w.z * bb.z + w.w * bb.w;
        }
        acc += __shfl_xor(acc, 1);
        acc += __shfl_xor(acc, 2);
        if (part == 0) b12[row] = acc + b2[row];
    } else if (bid == 196) {
        // ---- entries
        for (int t = tid; t <= B; t += 512) {
            if (t == B) {
                off[t] = T;
            } else {
                int lo = 0, hi = T;
                while (lo < hi) {
                    int mid = (lo + hi) >> 1;
                    if (db[mid] < t) lo = mid + 1; else hi = mid;
                }
                off[t] = lo;
            }
        }
        __syncthreads();
        for (int t = tid; t < B; t += 512)
            nch[t] = (off[t + 1] - off[t] + 63) >> 6;
        __syncthreads();
        if (tid == 0) {
            int s = 0;
            for (int i = 0; i < B; ++i) { scan[i] = s; s += nch[i]; }
            scan[B] = s;
        }
        __syncthreads();
        for (int t = tid; t < B; t += 512) {
            int cnt = off[t + 1] - off[t];
            for (int j = 0; j < nch[t]; ++j) {
                int v = cnt - j * 64;
                if (v > 64) v = 64;
                entries[scan[t] + j] = make_int4(t, off[t] + j * 64, v, 0);
            }
        }
        int total = scan[B];
        for (int i = total + tid; i < maxent; i += 512)
            entries[i] = make_int4(0, 0, 0, 0);
    } else {
        // ---- zero num/den (2*B*512 floats = 131072)
        const int idx = (bid - 197) * 512 + tid;   // 0..16383
        float4 z = {0.0f, 0.0f, 0.0f, 0.0f};
        *(float4*)(numden + (size_t)idx * 8) = z;
        *(float4*)(numden + (size_t)idx * 8 + 4) = z;
    }
}

// ---------------------------------------------------------------------------
// Main fused kernel: one block = 64 nodes of one batch, 512 threads (8 waves),
// 2 blocks/CU (LDS exactly 64KB) -> 16 waves/CU.
// Phase 1: LayerNorm, branch-free, 4-row ILP groups, XOR-swizzled LDS store.
// Phase 2: dual GEMM; wave owns 64 cols; A-frags from swizzled LDS
//   (ds_read_b128), B-frags from PACKED layout -> contiguous 1KB coalesced
//   global_load_dwordx4 per fragment.
// Epilogue: e=exp(feat); per-column sum(e), sum(e*cap); 2 atomics/col.
// ---------------------------------------------------------------------------
__global__ __launch_bounds__(512, 4)
void esa_fused(const float* __restrict__ x, const float* __restrict__ gamma,
               const float* __restrict__ beta, const short* __restrict__ W1p,
               const short* __restrict__ W12p, const float* __restrict__ b1,
               const float* __restrict__ b12, const int4* __restrict__ entries,
               float* __restrict__ num, float* __restrict__ den) {
    __shared__ short ylds[64 * 512];   // 65,536 B exactly -> 2 blocks/CU
    const int4 e = entries[blockIdx.x];
    const int bat = e.x, start = e.y, valid = e.z;
    if (valid <= 0) return;

    const int tid = threadIdx.x;
    const int wave = tid >> 6;          // 0..7
    const int lane = tid & 63;
    const int quad = lane >> 4;
    const int l16 = lane & 15;

    // ---- Phase 1: LayerNorm, rows wave*8..+7, lane owns 8 cols. Branch-free.
    const float4 g0 = *(const float4*)(gamma + lane * 8);
    const float4 g1 = *(const float4*)(gamma + lane * 8 + 4);
    const float4 be0 = *(const float4*)(beta + lane * 8);
    const float4 be1 = *(const float4*)(beta + lane * 8 + 4);

#pragma unroll
    for (int g = 0; g < 2; ++g) {               // two ILP groups of 4 rows
        float4 ra[4], rb[4];
        float s[4], ss[4];
#pragma unroll
        for (int r = 0; r < 4; ++r) {
            const int m = wave * 8 + g * 4 + r;
            const int mc = m < valid ? m : valid - 1;   // clamp: always in-batch
            const float* xr = x + (size_t)(start + mc) * 512 + lane * 8;
            ra[r] = *(const float4*)xr;
            rb[r] = *(const float4*)(xr + 4);
        }
#pragma unroll
        for (int r = 0; r < 4; ++r) {
            s[r] = ra[r].x + ra[r].y + ra[r].z + ra[r].w +
                   rb[r].x + rb[r].y + rb[r].z + rb[r].w;
            ss[r] = ra[r].x * ra[r].x + ra[r].y * ra[r].y + ra[r].z * ra[r].z +
                    ra[r].w * ra[r].w + rb[r].x * rb[r].x + rb[r].y * rb[r].y +
                    rb[r].z * rb[r].z + rb[r].w * rb[r].w;
        }
#pragma unroll
        for (int o = 1; o <= 32; o <<= 1) {     // 4 interleaved chains
#pragma unroll
            for (int r = 0; r < 4; ++r) {
                s[r] += __shfl_xor(s[r], o);
                ss[r] += __shfl_xor(ss[r], o);
            }
        }
#pragma unroll
        for (int r = 0; r < 4; ++r) {
            const int m = wave * 8 + g * 4 + r;
            const float mu = s[r] * (1.0f / 512.0f);
            const float var = ss[r] * (1.0f / 512.0f) - mu * mu;
            const float rstd = rsqrtf(var + 1e-5f);
            short8 outv;
            outv[0] = f2bf((ra[r].x - mu) * rstd * g0.x + be0.x);
            outv[1] = f2bf((ra[r].y - mu) * rstd * g0.y + be0.y);
            outv[2] = f2bf((ra[r].z - mu) * rstd * g0.z + be0.z);
            outv[3] = f2bf((ra[r].w - mu) * rstd * g0.w + be0.w);
            outv[4] = f2bf((rb[r].x - mu) * rstd * g1.x + be1.x);
            outv[5] = f2bf((rb[r].y - mu) * rstd * g1.y + be1.y);
            outv[6] = f2bf((rb[r].z - mu) * rstd * g1.z + be1.z);
            outv[7] = f2bf((rb[r].w - mu) * rstd * g1.w + be1.w);
            // XOR swizzle: column-block lane stored at lane ^ (m&7)
            *(short8*)&ylds[m * 512 + ((lane ^ (m & 7)) * 8)] = outv;
        }
    }
    __syncthreads();

    // ---- Phase 2: dual GEMM + epilogue. Wave owns cols [wave*64, +64).
    const int xr7 = l16 & 7;
    const short* abase = ylds + l16 * 512;

    for (int grp = 0; grp < 2; ++grp) {
        const int n0 = wave * 64 + grp * 32;
        const int ntile0 = n0 >> 4;           // wave*4 + grp*2
        f32x4 acc_c[2][4], acc_f[2][4];
#pragma unroll
        for (int nt = 0; nt < 2; ++nt)
#pragma unroll
            for (int mt = 0; mt < 4; ++mt) {
                acc_c[nt][mt] = (f32x4)0.0f;
                acc_f[nt][mt] = (f32x4)0.0f;
            }
        // packed B bases: lane-contiguous 1KB per (ntile, k0) chunk
        const short* w1t0 = W1p + (size_t)ntile0 * 8192 + lane * 8;
        const short* w1t1 = w1t0 + 8192;
        const short* w2t0 = W12p + (size_t)ntile0 * 8192 + lane * 8;
        const short* w2t1 = w2t0 + 8192;

#pragma unroll 2
        for (int k0 = 0; k0 < 16; ++k0) {
            // swizzled A-frag address: column block (4k0+quad) ^ (l16&7)
            const int blk = ((k0 << 2) | quad) ^ xr7;
            const short* ap = abase + blk * 8;
            short8 afr[4];
#pragma unroll
            for (int mt = 0; mt < 4; ++mt)
                afr[mt] = *(const short8*)(ap + mt * 16 * 512);
            const short8 b10 = *(const short8*)(w1t0 + k0 * 512);
            const short8 b11 = *(const short8*)(w1t1 + k0 * 512);
            const short8 b20 = *(const short8*)(w2t0 + k0 * 512);
            const short8 b21 = *(const short8*)(w2t1 + k0 * 512);
#pragma unroll
            for (int mt = 0; mt < 4; ++mt) {
                acc_c[0][mt] = __builtin_amdgcn_mfma_f32_16x16x32_bf16(
                    afr[mt], b10, acc_c[0][mt], 0, 0, 0);
                acc_c[1][mt] = __builtin_amdgcn_mfma_f32_16x16x32_bf16(
                    afr[mt], b11, acc_c[1][mt], 0, 0, 0);
                acc_f[0][mt] = __builtin_amdgcn_mfma_f32_16x16x32_bf16(
                    afr[mt], b20, acc_f[0][mt], 0, 0, 0);
                acc_f[1][mt] = __builtin_amdgcn_mfma_f32_16x16x32_bf16(
                    afr[mt], b21, acc_f[1][mt], 0, 0, 0);
            }
        }
        // Epilogue: C/D layout col=lane&15, row=quad*4+reg (m89-verified)
#pragma unroll
        for (int nt = 0; nt < 2; ++nt) {
            const int n = n0 + nt * 16 + l16;
            const float bb1 = b1[n];
            const float bb2 = b12[n];
            float se = 0.0f, sec = 0.0f;
#pragma unroll
            for (int mt = 0; mt < 4; ++mt) {
#pragma unroll
                for (int r2 = 0; r2 < 4; ++r2) {
                    const int m = mt * 16 + quad * 4 + r2;
                    const float cap = acc_c[nt][mt][r2] + bb1;
                    const float ft = acc_f[nt][mt][r2] + bb2;
                    if (m < valid) {
                        const float ev = __expf(ft);
                        se += ev;
                        sec += ev * cap;
                    }
                }
            }
            se += __shfl_xor(se, 16);
            se += __shfl_xor(se, 32);
            sec += __shfl_xor(sec, 16);
            sec += __shfl_xor(sec, 32);
            if (quad == 0) atomicAdd(&den[(size_t)bat * 512 + n], se);
            else if (quad == 1) atomicAdd(&num[(size_t)bat * 512 + n], sec);
        }
    }
}

__global__ __launch_bounds__(256)
void esa_finalize(const float* __restrict__ num, const float* __restrict__ den,
                  float* __restrict__ out, int n) {
    const int i = blockIdx.x * 256 + threadIdx.x;
    if (i < n) {
        const float d = den[i];
        out[i] = d > 0.0f ? num[i] / d : 0.0f;
    }
}

extern "C" void kernel_launch(void* const* d_in, const int* in_sizes, int n_in,
                              void* d_out, int out_size, void* d_ws, size_t ws_size,
                              hipStream_t stream) {
    const float* x = (const float*)d_in[0];
    const int* db = (const int*)d_in[1];
    // d_in[2] = max_nodes (unused: chunking derived from actual counts)
    const float* gamma = (const float*)d_in[3];
    const float* beta = (const float*)d_in[4];
    const float* W1 = (const float*)d_in[5];
    const float* b1 = (const float*)d_in[6];
    const float* W2 = (const float*)d_in[7];
    const float* b2 = (const float*)d_in[8];
    float* out = (float*)d_out;

    const int C = in_sizes[3];        // 512
    const int D = in_sizes[6];        // 512
    const int T = in_sizes[0] / C;    // 131072
    const int B = out_size / D;       // 128
    const int maxent = B + (T + 63) / 64;   // 2176

    char* ws = (char*)d_ws;
    short* W1p = (short*)(ws);                      // 512 KB packed
    short* W12p = (short*)(ws + 524288);            // 512 KB packed
    float* b12 = (float*)(ws + 1048576);            // 2 KB
    int4* entries = (int4*)(ws + 1050624);          // maxent*16
    size_t numoff = (1050624 + (size_t)maxent * 16 + 255) & ~(size_t)255;
    float* num = (float*)(ws + numoff);             // B*D*4
    float* den = (float*)(ws + numoff + (size_t)B * D * 4);

    esa_prep_all<<<PREP_GRID, 512, 0, stream>>>(W1, W2, b1, b2, db, T, B,
                                                W1p, W12p, b12, entries, maxent,
                                                num);
    esa_fused<<<maxent, 512, 0, stream>>>(x, gamma, beta, W1p, W12p, b1, b12,
                                          entries, num, den);
    esa_finalize<<<(B * D + 255) / 256, 256, 0, stream>>>(num, den, out, B * D);
}